// Round 3
// baseline (158.495 us; speedup 1.0000x reference)
//
#include <hip/hip_runtime.h>
#include <hip/hip_bf16.h>

namespace {

constexpr int Nn = 2048;
constexpr int Hh = 16;
constexpr int Dd = 64;
constexpr int ROWSTR = Hh * Dd;      // 1024 floats between consecutive tokens
constexpr int KVB = 64;              // KV tile rows
constexpr int NTILES = Nn / KVB;     // 32
constexpr int QB = 128;              // q-rows per block (each wave-group: 4 waves x 32)
constexpr int NQT = Nn / QB;         // 16

typedef __bf16 bf16x8 __attribute__((ext_vector_type(8)));
typedef __bf16 bf16x4 __attribute__((ext_vector_type(4)));
typedef float  f32x16 __attribute__((ext_vector_type(16)));

// K tile: row-major [64][64] bf16, 128B rows, 16B-granule XOR swizzle (b128-read friendly)
__device__ __forceinline__ int swzK(int row, int colByte) {
  return (row * 128 + colByte) ^ ((row & 7) << 4);
}
// V^T tile: [d=64][kv=64] bf16, extra bit-3 XOR (b64 reads stay 8B-aligned, 2-way free)
__device__ __forceinline__ int swzV(int row, int colByte) {
  return (row * 128 + colByte) ^ (((row & 7) << 4) | (((row >> 3) & 1) << 3));
}

struct StageRegs { float4 k[2]; float v[8]; };

// 512 threads stage one 64x64 KV tile: K as 2 float4/thread (coalesced 256B rows),
// V as 8 scalars/thread (d-contiguous across lanes, coalesced).
__device__ __forceinline__ void stage_issue(const float* kp, const float* vp,
                                            int kv0, int tid, StageRegs& s) {
#pragma unroll
  for (int it = 0; it < 2; ++it) {
    int idx = it * 512 + tid;
    int kvr = idx >> 4, c4 = idx & 15;
    s.k[it] = *(const float4*)(kp + (size_t)(kv0 + kvr) * ROWSTR + c4 * 4);
  }
#pragma unroll
  for (int it = 0; it < 2; ++it) {
    int idx = it * 512 + tid;
    int d8 = idx & 63, kv4 = idx >> 6;
#pragma unroll
    for (int i2 = 0; i2 < 4; ++i2)
      s.v[it * 4 + i2] = vp[(size_t)(kv0 + kv4 * 4 + i2) * ROWSTR + d8];
  }
}

__device__ __forceinline__ void stage_write(char* kb, char* vb, int tid,
                                            const StageRegs& s) {
#pragma unroll
  for (int it = 0; it < 2; ++it) {
    int idx = it * 512 + tid;
    int kvr = idx >> 4, c4 = idx & 15;
    bf16x4 w = { (__bf16)s.k[it].x, (__bf16)s.k[it].y,
                 (__bf16)s.k[it].z, (__bf16)s.k[it].w };
    *(bf16x4*)(kb + swzK(kvr, c4 * 8)) = w;
  }
#pragma unroll
  for (int it = 0; it < 2; ++it) {
    int idx = it * 512 + tid;
    int d8 = idx & 63, kv4 = idx >> 6;
    bf16x4 w = { (__bf16)s.v[it * 4 + 0], (__bf16)s.v[it * 4 + 1],
                 (__bf16)s.v[it * 4 + 2], (__bf16)s.v[it * 4 + 3] };
    *(bf16x4*)(vb + swzV(d8, kv4 * 8)) = w;
  }
}

__global__ __launch_bounds__(512, 4) void fattn_kernel(
    const float* __restrict__ Qg, const float* __restrict__ Kg,
    const float* __restrict__ Vg, const int* __restrict__ flag,
    float* __restrict__ Og) {
  // 4 tile buffers as 2 pairs; pair = (even tile, odd tile). 64 KB total.
  __shared__ __align__(16) char smem[2][2][16384];  // [pair][slot]: K 8KB @0, V^T 8KB @8192

  const int tid  = threadIdx.x;
  const int lane = tid & 63;
  const int wv   = tid >> 6;    // wave 0..7
  const int grp  = wv >> 2;     // 0: even KV tiles, 1: odd KV tiles
  const int wv4  = wv & 3;      // wave within group -> 32-row stripe
  const int l31  = lane & 31;
  const int g2   = lane >> 5;   // 0/1

  // grid = 512. Half 0 (bids 0..255) = heavy q-tiles (Tq=15..8) dispatched first;
  // half 1 = light q-tiles backfill. bid&7 groups 4 heads per XCD L2.
  const int bid  = blockIdx.x;
  const int half = bid >> 8;
  const int r    = bid & 255;
  const int bh   = ((r & 7) << 2) | (r >> 6);
  const int ti   = (r >> 3) & 7;
  const int b    = bh >> 4;
  const int h    = bh & 15;
  const int causal = flag[0];
  const int Tq   = half ? ti : (NQT - 1 - ti);

  const size_t base = ((size_t)b * Nn * Hh + h) * Dd;
  const float* qp = Qg + base;
  const float* kp = Kg + base;
  const float* vp = Vg + base;
  float*       op = Og + base;

  const float SCALE = 0.125f * 1.44269504088896340736f;  // 1/sqrt(64) * log2(e)

  const int qs = Tq * QB + wv4 * 32;              // wave's first q row (same for both grps)
  const int NI = causal ? (Tq + 1) : (NTILES / 2);  // barrier intervals (= tile pairs)
  // waves computing tile t = 2i+grp: grp0 all i; grp1 wv4<2 stop one interval early
  // (their last odd tile is fully above the diagonal)
  const int nCompute = (causal && grp == 1 && wv4 < 2) ? (NI - 1) : NI;

  // ---- Q fragments in registers (contiguous k-slot map) ----
  bf16x8 qf[4];
#pragma unroll
  for (int dc = 0; dc < 4; ++dc) {
    const float* qrow = qp + (size_t)(qs + l31) * ROWSTR + dc * 16 + g2 * 8;
    float4 a = *(const float4*)qrow;
    float4 c = *(const float4*)(qrow + 4);
    qf[dc][0] = (__bf16)(a.x * SCALE); qf[dc][1] = (__bf16)(a.y * SCALE);
    qf[dc][2] = (__bf16)(a.z * SCALE); qf[dc][3] = (__bf16)(a.w * SCALE);
    qf[dc][4] = (__bf16)(c.x * SCALE); qf[dc][5] = (__bf16)(c.y * SCALE);
    qf[dc][6] = (__bf16)(c.z * SCALE); qf[dc][7] = (__bf16)(c.w * SCALE);
  }

  f32x16 acc0 = {};   // O cols 0..31  (col = l31)
  f32x16 acc1 = {};   // O cols 32..63
  float m_run = -INFINITY;
  float l_run = 0.0f;

  StageRegs sA, sB;

  // ---- prologue: stage tiles 0,1 into pair 0 ----
  stage_issue(kp, vp, 0 * KVB, tid, sA);
  stage_issue(kp, vp, 1 * KVB, tid, sB);
  stage_write(&smem[0][0][0], &smem[0][0][0] + 8192, tid, sA);
  stage_write(&smem[0][1][0], &smem[0][1][0] + 8192, tid, sB);

  for (int i = 0; i < NI; ++i) {
    __syncthreads();
    const bool prefetch = (i + 1 < NI);

    // T14: issue next pair's global loads before compute
    if (prefetch) {
      stage_issue(kp, vp, (2 * i + 2) * KVB, tid, sA);
      stage_issue(kp, vp, (2 * i + 3) * KVB, tid, sB);
    }

    if (i < nCompute) {
      const int t = 2 * i + grp;
      const char* kb = &smem[i & 1][grp][0];
      const char* vb = kb + 8192;

      // ---- S^T = K . Q^T   (swapped: rows = kv, cols = q) ----
      f32x16 s0 = {}, s1 = {};
#pragma unroll
      for (int dc = 0; dc < 4; ++dc) {
        bf16x8 kf0 = *(const bf16x8*)(kb + swzK(l31,      32 * dc + 16 * g2));
        bf16x8 kf1 = *(const bf16x8*)(kb + swzK(32 + l31, 32 * dc + 16 * g2));
        s0 = __builtin_amdgcn_mfma_f32_32x32x16_bf16(kf0, qf[dc], s0, 0, 0, 0);
        s1 = __builtin_amdgcn_mfma_f32_32x32x16_bf16(kf1, qf[dc], s1, 0, 0, 0);
      }

      // ---- causal mask (diagonal pair = last interval only) ----
      if (causal && i == NI - 1) {
        const int kvb = t * KVB;
        const int qrow = qs + l31;
#pragma unroll
        for (int rr = 0; rr < 16; ++rr) {
          int rm = (rr & 3) + ((rr >> 2) << 3) + (g2 << 2);
          if (kvb + rm > qrow)      s0[rr] = -INFINITY;
          if (kvb + 32 + rm > qrow) s1[rr] = -INFINITY;
        }
      }

      // ---- online softmax (stats in q = l31 domain; 1 shfl_xor per reduce) ----
      float mt = -INFINITY;
#pragma unroll
      for (int rr = 0; rr < 16; ++rr) { mt = fmaxf(mt, s0[rr]); mt = fmaxf(mt, s1[rr]); }
      mt = fmaxf(mt, __shfl_xor(mt, 32));
      const float mnew = fmaxf(m_run, mt);
      float rs = 0.0f;
#pragma unroll
      for (int rr = 0; rr < 16; ++rr) {
        float p0 = exp2f(s0[rr] - mnew);
        float p1 = exp2f(s1[rr] - mnew);
        s0[rr] = p0; s1[rr] = p1;
        rs += p0 + p1;
      }
      rs += __shfl_xor(rs, 32);
      if (__all(mt <= m_run)) {          // no row max changed: skip rescale
        l_run += rs;
      } else {
        const float alpha = exp2f(m_run - mnew);
#pragma unroll
        for (int rr = 0; rr < 16; ++rr) {
          float at = __shfl(alpha, (rr & 3) + ((rr >> 2) << 3) + (g2 << 2));
          acc0[rr] *= at;
          acc1[rr] *= at;
        }
        l_run = l_run * alpha + rs;
        m_run = mnew;
      }

      // ---- P fragments: direct pass-through of S^T regs (split-4 k-slot map) ----
      bf16x8 pa[4];
#pragma unroll
      for (int kc = 0; kc < 4; ++kc) {
        const f32x16& sv = (kc < 2) ? s0 : s1;
        const int rbase = (kc & 1) * 8;
#pragma unroll
        for (int j = 0; j < 8; ++j) pa[kc][j] = (__bf16)sv[rbase + j];
      }

      // ---- O += P . V  (V read d-major from V^T, split-4 k-slot map) ----
#pragma unroll
      for (int kc = 0; kc < 4; ++kc) {
        const int cb = 32 * kc + 8 * g2;
#pragma unroll
        for (int df = 0; df < 2; ++df) {
          const int row = 32 * df + l31;
          bf16x4 v0 = *(const bf16x4*)(vb + swzV(row, cb));
          bf16x4 v1 = *(const bf16x4*)(vb + swzV(row, cb + 16));
          bf16x8 vf = __builtin_shufflevector(v0, v1, 0, 1, 2, 3, 4, 5, 6, 7);
          if (df == 0)
            acc0 = __builtin_amdgcn_mfma_f32_32x32x16_bf16(pa[kc], vf, acc0, 0, 0, 0);
          else
            acc1 = __builtin_amdgcn_mfma_f32_32x32x16_bf16(pa[kc], vf, acc1, 0, 0, 0);
        }
      }
    }

    // T14: convert + write next pair into the other buffer pair after compute
    if (prefetch) {
      char* kbA = &smem[(i + 1) & 1][0][0];
      char* kbB = &smem[(i + 1) & 1][1][0];
      stage_write(kbA, kbA + 8192, tid, sA);
      stage_write(kbB, kbB + 8192, tid, sB);
    }
  }

  // ---- merge group B into group A via LDS, then epilogue (A waves only) ----
  __syncthreads();   // all computes done; smem reusable
  if (grp == 1) {
    float* ab = (float*)(&smem[0][0][0] + wv4 * 8448);
#pragma unroll
    for (int rr = 0; rr < 16; ++rr) {
      int rm = (rr & 3) + ((rr >> 2) << 3) + (g2 << 2);
      ab[rm * 64 + l31]      = acc0[rr];
      ab[rm * 64 + 32 + l31] = acc1[rr];
    }
    if (g2 == 0) { ab[2048 + l31] = m_run; ab[2080 + l31] = l_run; }
  }
  __syncthreads();
  if (grp == 0) {
    const float* ab = (const float*)(&smem[0][0][0] + wv4 * 8448);
    const float mB = ab[2048 + l31];
    const float lB = ab[2080 + l31];
    const float mN = fmaxf(m_run, mB);
    const float aA = exp2f(m_run - mN);
    const float aB = exp2f(mB - mN);
    const float lT = l_run * aA + lB * aB;
    const float linv = 1.0f / lT;
#pragma unroll
    for (int rr = 0; rr < 16; ++rr) {
      const int rm = (rr & 3) + ((rr >> 2) << 3) + (g2 << 2);
      const float fA = __shfl(aA, rm);
      const float fB = __shfl(aB, rm);
      const float li = __shfl(linv, rm);
      const float o0 = acc0[rr] * fA + ab[rm * 64 + l31] * fB;
      const float o1 = acc1[rr] * fA + ab[rm * 64 + 32 + l31] * fB;
      const size_t row = (size_t)(qs + rm) * ROWSTR;
      op[row + l31]      = o0 * li;
      op[row + 32 + l31] = o1 * li;
    }
  }
}

}  // namespace

extern "C" void kernel_launch(void* const* d_in, const int* in_sizes, int n_in,
                              void* d_out, int out_size, void* d_ws, size_t ws_size,
                              hipStream_t stream) {
  (void)in_sizes; (void)n_in; (void)out_size; (void)d_ws; (void)ws_size;
  const float* q = (const float*)d_in[0];
  const float* k = (const float*)d_in[1];
  const float* v = (const float*)d_in[2];
  const int* flag = (const int*)d_in[3];
  float* out = (float*)d_out;
  fattn_kernel<<<dim3(512), dim3(512), 0, stream>>>(q, k, v, flag, out);
}

// Round 4
// 72.687 us; speedup vs baseline: 2.1805x; 2.1805x over previous
//
#include <hip/hip_runtime.h>
#include <hip/hip_bf16.h>

namespace {

constexpr int Nn = 2048;
constexpr int Hh = 16;
constexpr int Dd = 64;
constexpr int ROWSTR = Hh * Dd;      // 1024 floats between consecutive tokens
constexpr int KVB = 64;              // KV tile rows
constexpr int NTILES = Nn / KVB;     // 32
constexpr int QB = 128;              // q-rows per block (each wave-group: 4 waves x 32)
constexpr int NQT = Nn / QB;         // 16

typedef __bf16 bf16x8 __attribute__((ext_vector_type(8)));
typedef __bf16 bf16x4 __attribute__((ext_vector_type(4)));
typedef float  f32x16 __attribute__((ext_vector_type(16)));

// K tile: row-major [64][64] bf16, 128B rows, 16B-granule XOR swizzle (b128-read friendly)
__device__ __forceinline__ int swzK(int row, int colByte) {
  return (row * 128 + colByte) ^ ((row & 7) << 4);
}
// V^T tile: [d=64][kv=64] bf16, extra bit-3 XOR (b64 reads stay 8B-aligned, 2-way free)
__device__ __forceinline__ int swzV(int row, int colByte) {
  return (row * 128 + colByte) ^ (((row & 7) << 4) | (((row >> 3) & 1) << 3));
}

struct StageRegs { float4 k[2]; float v[8]; };  // 16 VGPRs while live

// 512 threads stage one 64x64 KV tile: K as 2 float4/thread (coalesced 256B rows),
// V as 8 scalars/thread (d-contiguous across lanes, coalesced).
__device__ __forceinline__ void stage_issue(const float* kp, const float* vp,
                                            int kv0, int tid, StageRegs& s) {
#pragma unroll
  for (int it = 0; it < 2; ++it) {
    int idx = it * 512 + tid;
    int kvr = idx >> 4, c4 = idx & 15;
    s.k[it] = *(const float4*)(kp + (size_t)(kv0 + kvr) * ROWSTR + c4 * 4);
  }
#pragma unroll
  for (int it = 0; it < 2; ++it) {
    int idx = it * 512 + tid;
    int d8 = idx & 63, kv4 = idx >> 6;
#pragma unroll
    for (int i2 = 0; i2 < 4; ++i2)
      s.v[it * 4 + i2] = vp[(size_t)(kv0 + kv4 * 4 + i2) * ROWSTR + d8];
  }
}

__device__ __forceinline__ void stage_write(char* kb, char* vb, int tid,
                                            const StageRegs& s) {
#pragma unroll
  for (int it = 0; it < 2; ++it) {
    int idx = it * 512 + tid;
    int kvr = idx >> 4, c4 = idx & 15;
    bf16x4 w = { (__bf16)s.k[it].x, (__bf16)s.k[it].y,
                 (__bf16)s.k[it].z, (__bf16)s.k[it].w };
    *(bf16x4*)(kb + swzK(kvr, c4 * 8)) = w;
  }
#pragma unroll
  for (int it = 0; it < 2; ++it) {
    int idx = it * 512 + tid;
    int d8 = idx & 63, kv4 = idx >> 6;
    bf16x4 w = { (__bf16)s.v[it * 4 + 0], (__bf16)s.v[it * 4 + 1],
                 (__bf16)s.v[it * 4 + 2], (__bf16)s.v[it * 4 + 3] };
    *(bf16x4*)(vb + swzV(d8, kv4 * 8)) = w;
  }
}

__global__ __launch_bounds__(512, 2) void fattn_kernel(
    const float* __restrict__ Qg, const float* __restrict__ Kg,
    const float* __restrict__ Vg, const int* __restrict__ flag,
    float* __restrict__ Og) {
  // 4 tile buffers as 2 pairs; pair = (even tile, odd tile). 64 KB total.
  __shared__ __align__(16) char smem[2][2][16384];  // [pair][slot]: K 8KB @0, V^T 8KB @8192

  const int tid  = threadIdx.x;
  const int lane = tid & 63;
  const int wv   = tid >> 6;    // wave 0..7
  const int grp  = wv >> 2;     // 0: even KV tiles, 1: odd KV tiles
  const int wv4  = wv & 3;      // wave within group -> 32-row q stripe
  const int l31  = lane & 31;
  const int g2   = lane >> 5;   // 0/1

  // grid = 512. Half 0 (bids 0..255) = heavy q-tiles (Tq=15..8) dispatched first;
  // half 1 = light q-tiles backfill. bid&7 groups 4 heads per XCD L2.
  const int bid  = blockIdx.x;
  const int half = bid >> 8;
  const int r    = bid & 255;
  const int bh   = ((r & 7) << 2) | (r >> 6);
  const int ti   = (r >> 3) & 7;
  const int b    = bh >> 4;
  const int h    = bh & 15;
  const int causal = flag[0];
  const int Tq   = half ? ti : (NQT - 1 - ti);

  const size_t base = ((size_t)b * Nn * Hh + h) * Dd;
  const float* qp = Qg + base;
  const float* kp = Kg + base;
  const float* vp = Vg + base;
  float*       op = Og + base;

  const float SCALE = 0.125f * 1.44269504088896340736f;  // 1/sqrt(64) * log2(e)

  const int qs = Tq * QB + wv4 * 32;              // wave's first q row (same for both grps)
  const int NI = causal ? (Tq + 1) : (NTILES / 2);  // barrier intervals (= tile pairs)
  // grp1 waves with wv4<2: last odd tile is fully above the diagonal -> skip
  const int nCompute = (causal && grp == 1 && wv4 < 2) ? (NI - 1) : NI;

  // ---- Q fragments in registers (contiguous k-slot map) ----
  bf16x8 qf[4];
#pragma unroll
  for (int dc = 0; dc < 4; ++dc) {
    const float* qrow = qp + (size_t)(qs + l31) * ROWSTR + dc * 16 + g2 * 8;
    float4 a = *(const float4*)qrow;
    float4 c = *(const float4*)(qrow + 4);
    qf[dc][0] = (__bf16)(a.x * SCALE); qf[dc][1] = (__bf16)(a.y * SCALE);
    qf[dc][2] = (__bf16)(a.z * SCALE); qf[dc][3] = (__bf16)(a.w * SCALE);
    qf[dc][4] = (__bf16)(c.x * SCALE); qf[dc][5] = (__bf16)(c.y * SCALE);
    qf[dc][6] = (__bf16)(c.z * SCALE); qf[dc][7] = (__bf16)(c.w * SCALE);
  }

  f32x16 acc0 = {};   // O cols 0..31  (col = l31)
  f32x16 acc1 = {};   // O cols 32..63
  float m_run = -INFINITY;
  float l_run = 0.0f;

  StageRegs st;       // single staging register set; lifetimes disjoint

  // ---- prologue: stage tiles 0,1 into pair 0 ----
  stage_issue(kp, vp, 0 * KVB, tid, st);
  stage_write(&smem[0][0][0], &smem[0][0][0] + 8192, tid, st);
  stage_issue(kp, vp, 1 * KVB, tid, st);
  stage_write(&smem[0][1][0], &smem[0][1][0] + 8192, tid, st);

  for (int i = 0; i < NI; ++i) {
    __syncthreads();
    const bool prefetch = (i + 1 < NI);
    const char* kb = &smem[i & 1][grp][0];
    const char* vb = kb + 8192;
    char* nkA = &smem[(i + 1) & 1][0][0];
    char* nkB = &smem[(i + 1) & 1][1][0];

    // issue next even tile's loads; latency hides under QK^T + softmax
    if (prefetch) stage_issue(kp, vp, (2 * i + 2) * KVB, tid, st);

    f32x16 s0, s1;
    bf16x8 pa[4];
    const bool doC = (i < nCompute);
    if (doC) {
      // ---- S^T = K . Q^T   (swapped: rows = kv, cols = q) ----
      s0 = (f32x16){}; s1 = (f32x16){};
#pragma unroll
      for (int dc = 0; dc < 4; ++dc) {
        bf16x8 kf0 = *(const bf16x8*)(kb + swzK(l31,      32 * dc + 16 * g2));
        bf16x8 kf1 = *(const bf16x8*)(kb + swzK(32 + l31, 32 * dc + 16 * g2));
        s0 = __builtin_amdgcn_mfma_f32_32x32x16_bf16(kf0, qf[dc], s0, 0, 0, 0);
        s1 = __builtin_amdgcn_mfma_f32_32x32x16_bf16(kf1, qf[dc], s1, 0, 0, 0);
      }

      // ---- causal mask (diagonal interval only) ----
      if (causal && i == NI - 1) {
        const int kvb = (2 * i + grp) * KVB;
        const int qrow = qs + l31;
#pragma unroll
        for (int rr = 0; rr < 16; ++rr) {
          int rm = (rr & 3) + ((rr >> 2) << 3) + (g2 << 2);
          if (kvb + rm > qrow)      s0[rr] = -INFINITY;
          if (kvb + 32 + rm > qrow) s1[rr] = -INFINITY;
        }
      }

      // ---- online softmax (stats in q = l31 domain; 1 shfl_xor per reduce) ----
      float mt = -INFINITY;
#pragma unroll
      for (int rr = 0; rr < 16; ++rr) { mt = fmaxf(mt, s0[rr]); mt = fmaxf(mt, s1[rr]); }
      mt = fmaxf(mt, __shfl_xor(mt, 32));
      const float mnew = fmaxf(m_run, mt);
      float rs = 0.0f;
#pragma unroll
      for (int rr = 0; rr < 16; ++rr) {
        float p0 = exp2f(s0[rr] - mnew);
        float p1 = exp2f(s1[rr] - mnew);
        s0[rr] = p0; s1[rr] = p1;
        rs += p0 + p1;
      }
      rs += __shfl_xor(rs, 32);
      if (__all(mt <= m_run)) {          // no row max changed: skip rescale
        l_run += rs;
      } else {
        const float alpha = exp2f(m_run - mnew);
#pragma unroll
        for (int rr = 0; rr < 16; ++rr) {
          float at = __shfl(alpha, (rr & 3) + ((rr >> 2) << 3) + (g2 << 2));
          acc0[rr] *= at;
          acc1[rr] *= at;
        }
        l_run = l_run * alpha + rs;
        m_run = mnew;
      }

      // ---- P fragments: direct pass-through of S^T regs (split-4 k-slot map) ----
#pragma unroll
      for (int kc = 0; kc < 4; ++kc) {
        const f32x16& sv = (kc < 2) ? s0 : s1;
        const int rbase = (kc & 1) * 8;
#pragma unroll
        for (int j = 0; j < 8; ++j) pa[kc][j] = (__bf16)sv[rbase + j];
      }
    }

    // write even tile (st -> LDS), then issue odd tile's loads (hide under PV)
    if (prefetch) {
      stage_write(nkA, nkA + 8192, tid, st);
      stage_issue(kp, vp, (2 * i + 3) * KVB, tid, st);
    }

    if (doC) {
      // ---- O += P . V  (V read d-major from V^T, split-4 k-slot map) ----
#pragma unroll
      for (int kc = 0; kc < 4; ++kc) {
        const int cb = 32 * kc + 8 * g2;
#pragma unroll
        for (int df = 0; df < 2; ++df) {
          const int row = 32 * df + l31;
          bf16x4 v0 = *(const bf16x4*)(vb + swzV(row, cb));
          bf16x4 v1 = *(const bf16x4*)(vb + swzV(row, cb + 16));
          bf16x8 vf = __builtin_shufflevector(v0, v1, 0, 1, 2, 3, 4, 5, 6, 7);
          if (df == 0)
            acc0 = __builtin_amdgcn_mfma_f32_32x32x16_bf16(pa[kc], vf, acc0, 0, 0, 0);
          else
            acc1 = __builtin_amdgcn_mfma_f32_32x32x16_bf16(pa[kc], vf, acc1, 0, 0, 0);
        }
      }
    }

    // write odd tile
    if (prefetch) stage_write(nkB, nkB + 8192, tid, st);
  }

  // ---- merge group B into group A via LDS, then epilogue (A waves only) ----
  __syncthreads();   // all computes done; smem reusable
  if (grp == 1) {
    float* ab = (float*)(&smem[0][0][0] + wv4 * 8448);
#pragma unroll
    for (int rr = 0; rr < 16; ++rr) {
      int rm = (rr & 3) + ((rr >> 2) << 3) + (g2 << 2);
      ab[rm * 64 + l31]      = acc0[rr];
      ab[rm * 64 + 32 + l31] = acc1[rr];
    }
    if (g2 == 0) { ab[2048 + l31] = m_run; ab[2080 + l31] = l_run; }
  }
  __syncthreads();
  if (grp == 0) {
    const float* ab = (const float*)(&smem[0][0][0] + wv4 * 8448);
    const float mB = ab[2048 + l31];
    const float lB = ab[2080 + l31];
    const float mN = fmaxf(m_run, mB);
    const float aA = exp2f(m_run - mN);
    const float aB = exp2f(mB - mN);
    const float lT = l_run * aA + lB * aB;
    const float linv = 1.0f / lT;
#pragma unroll
    for (int rr = 0; rr < 16; ++rr) {
      const int rm = (rr & 3) + ((rr >> 2) << 3) + (g2 << 2);
      const float fA = __shfl(aA, rm);
      const float fB = __shfl(aB, rm);
      const float li = __shfl(linv, rm);
      const float o0 = acc0[rr] * fA + ab[rm * 64 + l31] * fB;
      const float o1 = acc1[rr] * fA + ab[rm * 64 + 32 + l31] * fB;
      const size_t row = (size_t)(qs + rm) * ROWSTR;
      op[row + l31]      = o0 * li;
      op[row + 32 + l31] = o1 * li;
    }
  }
}

}  // namespace

extern "C" void kernel_launch(void* const* d_in, const int* in_sizes, int n_in,
                              void* d_out, int out_size, void* d_ws, size_t ws_size,
                              hipStream_t stream) {
  (void)in_sizes; (void)n_in; (void)out_size; (void)d_ws; (void)ws_size;
  const float* q = (const float*)d_in[0];
  const float* k = (const float*)d_in[1];
  const float* v = (const float*)d_in[2];
  const int* flag = (const int*)d_in[3];
  float* out = (float*)d_out;
  fattn_kernel<<<dim3(512), dim3(512), 0, stream>>>(q, k, v, flag, out);
}